// Round 8
// baseline (374.057 us; speedup 1.0000x reference)
//
#include <hip/hip_runtime.h>
#include <hip/hip_bf16.h>
#include <math.h>

#define CAP 64
#define GG 2048     // conv grid (colpart rows)
#define RB 32       // colpart rows per stage-A block (GG/RB = 64 stage-A blocks)
#define PCHUNK 4096 // edges per partition block-chunk
#define BINCAP 225000

typedef __hip_bfloat16 bf16;
typedef unsigned int uint;
typedef unsigned short ushort;

__device__ __forceinline__ bf16  f2b(float x) { return __float2bfloat16(x); }
// packed pos/neg: low 16 bits = bf16(pos), high 16 bits = bf16(neg)
__device__ __forceinline__ float posf(uint u) { return __uint_as_float(u << 16); }
__device__ __forceinline__ float negf(uint u) { return __uint_as_float(u & 0xFFFF0000u); }
__device__ __forceinline__ uint  packbf(float p, float n) {
    bf16 bp = f2b(p), bn = f2b(n);
    ushort up = *reinterpret_cast<ushort*>(&bp);
    ushort un = *reinterpret_cast<ushort*>(&bn);
    return (uint)up | ((uint)un << 16);
}
__device__ __forceinline__ float rdlane_f(float v, int k) {
    return __uint_as_float(__builtin_amdgcn_readlane(__float_as_uint(v), k));
}

// ---- P1: partition edges into 8 col-range bins (chunked LDS histogram) ----
__global__ __launch_bounds__(256) void partition_edges(
        const int* __restrict__ row, const int* __restrict__ col,
        int2* __restrict__ bins, int* __restrict__ bincur, int E, int bound) {
    __shared__ int lcnt[8];
    __shared__ int lbase[8];
    for (int chunk = blockIdx.x * PCHUNK; chunk < E; chunk += gridDim.x * PCHUNK) {
        int end = chunk + PCHUNK < E ? chunk + PCHUNK : E;
        if (threadIdx.x < 8) lcnt[threadIdx.x] = 0;
        __syncthreads();
        for (int e = chunk + threadIdx.x; e < end; e += blockDim.x)
            atomicAdd(&lcnt[col[e] / bound], 1);
        __syncthreads();
        if (threadIdx.x < 8) {
            lbase[threadIdx.x] = atomicAdd(&bincur[threadIdx.x], lcnt[threadIdx.x]);
            lcnt[threadIdx.x] = 0;
        }
        __syncthreads();
        for (int e = chunk + threadIdx.x; e < end; e += blockDim.x) {
            int c = col[e], r = row[e];
            int g = c / bound;
            int dst = lbase[g] + atomicAdd(&lcnt[g], 1);
            if (dst < BINCAP) bins[(size_t)g * BINCAP + dst] = make_int2(r, c);
        }
        __syncthreads();
    }
}

// ---- P2: place from bins; group g = blockIdx&7 stays on one XCD so its
// 3.2 MB bucket window is L2-resident (bin read is only 1.6 MB, no thrash) --
__global__ __launch_bounds__(256) void place_binned(
        const int2* __restrict__ bins, const int* __restrict__ bincur,
        int* __restrict__ bucket, int* __restrict__ cnt) {
    int g  = blockIdx.x & 7;
    int kb = blockIdx.x >> 3;
    int K  = gridDim.x >> 3;
    int n  = bincur[g];
    if (n > BINCAP) n = BINCAP;
    const int2* b = bins + (size_t)g * BINCAP;
    for (int i = kb * blockDim.x + threadIdx.x; i < n; i += K * blockDim.x) {
        int2 e = b[i];
        int pos = atomicAdd(&cnt[e.y], 1);
        if (pos < CAP) bucket[(size_t)e.y * CAP + pos] = e.x;
    }
}

// ---- layer-1 GEMM: coalesced row load + readlane broadcast ----------------
__global__ __launch_bounds__(256) void gemm1_both(
        const float* __restrict__ X, const float* __restrict__ W,
        const int* __restrict__ perm, const int* __restrict__ cnt,
        uint* __restrict__ out, int n) {
    int lane = threadIdx.x & 63, wid = threadIdx.x >> 6;
    float w[64];
#pragma unroll
    for (int k = 0; k < 64; k++) w[k] = W[k * 64 + lane];
    int wstart = blockIdx.x * 4 + wid, wstride = gridDim.x * 4;
    for (int v = wstart; v < n; v += wstride) {
        float xp = X[(size_t)v * 64 + lane];
        float xn = X[(size_t)perm[v] * 64 + lane];
        float dv = rsqrtf((float)cnt[v] + 1.0f);
        float ap0 = 0.f, ap1 = 0.f, an0 = 0.f, an1 = 0.f;
#pragma unroll
        for (int k = 0; k < 64; k += 2) {
            float xp0 = rdlane_f(xp, k),     xn0 = rdlane_f(xn, k);
            float xp1 = rdlane_f(xp, k + 1), xn1 = rdlane_f(xn, k + 1);
            ap0 = fmaf(xp0, w[k], ap0);     an0 = fmaf(xn0, w[k], an0);
            ap1 = fmaf(xp1, w[k + 1], ap1); an1 = fmaf(xn1, w[k + 1], an1);
        }
        out[(size_t)v * 64 + lane] = packbf((ap0 + ap1) * dv, (an0 + an1) * dv);
    }
}

// ---- layer-2 GEMM, packed in/out: one readlane serves both branches -------
__global__ __launch_bounds__(256) void gemm2_both(
        const uint* __restrict__ H, const float* __restrict__ W,
        const int* __restrict__ cnt, uint* __restrict__ out, int n) {
    int lane = threadIdx.x & 63, wid = threadIdx.x >> 6;
    float w[64];
#pragma unroll
    for (int k = 0; k < 64; k++) w[k] = W[k * 64 + lane];
    int wstart = blockIdx.x * 4 + wid, wstride = gridDim.x * 4;
    for (int v = wstart; v < n; v += wstride) {
        uint hv = H[(size_t)v * 64 + lane];
        float dv = rsqrtf((float)cnt[v] + 1.0f);
        float ap0 = 0.f, ap1 = 0.f, an0 = 0.f, an1 = 0.f;
#pragma unroll
        for (int k = 0; k < 64; k += 2) {
            uint u0 = __builtin_amdgcn_readlane(hv, k);
            uint u1 = __builtin_amdgcn_readlane(hv, k + 1);
            ap0 = fmaf(posf(u0), w[k], ap0);     an0 = fmaf(negf(u0), w[k], an0);
            ap1 = fmaf(posf(u1), w[k + 1], ap1); an1 = fmaf(negf(u1), w[k + 1], an1);
        }
        out[(size_t)v * 64 + lane] = packbf((ap0 + ap1) * dv, (an0 + an1) * dv);
    }
}

// ---- fused GCN aggregation, packed pos/neg (wave/node, lane=dim) ----------
// g pre-scaled by dis:  res = dv*(sum_in g[r] + g[v]) + bias
// MODE 0: relu -> out.  MODE 1: raw -> out, pos col-partials -> colpart.
template <int MODE>
__global__ __launch_bounds__(256) void conv_packed(
        const uint* __restrict__ g, const int* __restrict__ bucket,
        const int* __restrict__ cnt, const float* __restrict__ bias,
        uint* __restrict__ out, float* __restrict__ colpart, int n) {
    int lane = threadIdx.x & 63, wid = threadIdx.x >> 6;
    __shared__ float s[256];
    float colp  = 0.f;
    float blane = bias[lane];
    int wstart = blockIdx.x * 4 + wid, wstride = gridDim.x * 4;
    for (int v = wstart; v < n; v += wstride) {
        int cf = cnt[v];
        int c  = cf > CAP ? CAP : cf;
        float dv = rsqrtf((float)cf + 1.0f);
        size_t vo = (size_t)v * 64 + lane;
        uint su = g[vo];
        float a0p = posf(su), a1p = 0.f, a2p = 0.f, a3p = 0.f;   // self in a0
        float a0n = negf(su), a1n = 0.f, a2n = 0.f, a3n = 0.f;
        const int*  bk  = bucket + (size_t)v * CAP;
        const int4* bk4 = (const int4*)bk;
        int nq8 = c >> 3;
        for (int q = 0; q < nq8; q++) {
            int4 ra = bk4[2 * q], rb = bk4[2 * q + 1];
            uint u0 = g[(size_t)ra.x * 64 + lane];
            uint u1 = g[(size_t)ra.y * 64 + lane];
            uint u2 = g[(size_t)ra.z * 64 + lane];
            uint u3 = g[(size_t)ra.w * 64 + lane];
            uint u4 = g[(size_t)rb.x * 64 + lane];
            uint u5 = g[(size_t)rb.y * 64 + lane];
            uint u6 = g[(size_t)rb.z * 64 + lane];
            uint u7 = g[(size_t)rb.w * 64 + lane];
            a0p += posf(u0) + posf(u4); a0n += negf(u0) + negf(u4);
            a1p += posf(u1) + posf(u5); a1n += negf(u1) + negf(u5);
            a2p += posf(u2) + posf(u6); a2n += negf(u2) + negf(u6);
            a3p += posf(u3) + posf(u7); a3n += negf(u3) + negf(u7);
        }
        int i = nq8 << 3;
        if (c - i >= 4) {
            int4 r = bk4[i >> 2];
            uint u0 = g[(size_t)r.x * 64 + lane];
            uint u1 = g[(size_t)r.y * 64 + lane];
            uint u2 = g[(size_t)r.z * 64 + lane];
            uint u3 = g[(size_t)r.w * 64 + lane];
            a0p += posf(u0); a0n += negf(u0);
            a1p += posf(u1); a1n += negf(u1);
            a2p += posf(u2); a2n += negf(u2);
            a3p += posf(u3); a3n += negf(u3);
            i += 4;
        }
        for (; i < c; i++) {
            uint u = g[(size_t)bk[i] * 64 + lane];
            a0p += posf(u);
            a0n += negf(u);
        }
        float sp = (a0p + a1p) + (a2p + a3p);
        float sn = (a0n + a1n) + (a2n + a3n);
        float rp = fmaf(dv, sp, blane);
        float rn = fmaf(dv, sn, blane);
        if (MODE == 0) {
            out[vo] = packbf(fmaxf(rp, 0.f), fmaxf(rn, 0.f));
        } else {
            out[vo] = packbf(rp, rn);
            colp += rp;           // f32 partial (pre-rounding) for summary
        }
    }
    if (MODE == 1) {
        s[wid * 64 + lane] = colp;
        __syncthreads();
        if (wid == 0) {
            float t = s[lane] + s[64 + lane] + s[128 + lane] + s[192 + lane];
            colpart[(size_t)blockIdx.x * 64 + lane] = t;
        }
    }
}

// ---- stage A: sum RB colpart rows per block -> colpart2 (GG/RB rows) ------
__global__ __launch_bounds__(256) void colreduce_kernel(
        const float* __restrict__ colpart, float* __restrict__ colpart2) {
    int lane = threadIdx.x & 63, w = threadIdx.x >> 6;
    __shared__ float s4[4][64];
    float t = 0.f;
    int base = blockIdx.x * RB;
    for (int g = w; g < RB; g += 4) t += colpart[(size_t)(base + g) * 64 + lane];
    s4[w][lane] = t;
    __syncthreads();
    if (w == 0)
        colpart2[(size_t)blockIdx.x * 64 + lane] =
            s4[0][lane] + s4[1][lane] + s4[2][lane] + s4[3][lane];
}

// ---- summary + ws = W_dgi @ sigmoid(mean(pos_z)) --------------------------
__global__ void summary_kernel(const float* __restrict__ colpart,
                               const float* __restrict__ Wdgi,
                               float* __restrict__ wsv, int G, float invN) {
    __shared__ float sm[64];
    __shared__ float s4[4][64];
    int lane = threadIdx.x & 63, w = threadIdx.x >> 6;
    float t = 0.f;
    for (int g = w; g < G; g += 4) t += colpart[(size_t)g * 64 + lane];
    s4[w][lane] = t;
    __syncthreads();
    if (w == 0) {
        t = s4[0][lane] + s4[1][lane] + s4[2][lane] + s4[3][lane];
        sm[lane] = 1.f / (1.f + expf(-t * invN));
    }
    __syncthreads();
    if (threadIdx.x < 64) {
        float a = 0.f;
        for (int j = 0; j < 64; j++) a += Wdgi[threadIdx.x * 64 + j] * sm[j];
        wsv[threadIdx.x] = a;
    }
}

// ---- both losses in one pass (packed z) -----------------------------------
__global__ __launch_bounds__(256) void loss_kernel(
        const uint* __restrict__ z, const float* __restrict__ wsv,
        float* __restrict__ lossacc, int n) {
    int lane = threadIdx.x & 63, wid = threadIdx.x >> 6;
    __shared__ float s[16];
    float wlane = wsv[lane];
    float lp = 0.f, ln = 0.f;
    int wstart = blockIdx.x * 4 + wid, wstride = gridDim.x * 4;
    for (int v = wstart; v < n; v += wstride) {
        uint u = z[(size_t)v * 64 + lane];
        float p = posf(u) * wlane;
        float q = negf(u) * wlane;
        for (int off = 32; off; off >>= 1) {
            p += __shfl_xor(p, off, 64);
            q += __shfl_xor(q, off, 64);
        }
        if (lane == 0) {
            lp += -logf(1.f / (1.f + expf(-p)) + 1e-15f);   // -log(sigmoid(p)+eps)
            ln += -logf(1.f / (1.f + expf( q)) + 1e-15f);   // -log(1-sigmoid(q)+eps)
        }
    }
    if (lane == 0) { s[wid] = lp; s[8 + wid] = ln; }
    __syncthreads();
    if (threadIdx.x == 0) atomicAdd(&lossacc[0], s[0] + s[1] + s[2] + s[3]);
    if (threadIdx.x == 1) atomicAdd(&lossacc[1], s[8] + s[9] + s[10] + s[11]);
}

__global__ void finalize_kernel(const float* __restrict__ lossacc,
                                float* __restrict__ out, float invN) {
    out[0] = (lossacc[0] + lossacc[1]) * invN;
}

// ---------------------------------------------------------------------------
extern "C" void kernel_launch(void* const* d_in, const int* in_sizes, int n_in,
                              void* d_out, int out_size, void* d_ws, size_t ws_size,
                              hipStream_t stream) {
    const float* x    = (const float*)d_in[0];
    const float* W1   = (const float*)d_in[1];
    const float* b1   = (const float*)d_in[2];
    const float* W2   = (const float*)d_in[3];
    const float* b2   = (const float*)d_in[4];
    const float* Wdgi = (const float*)d_in[5];
    const int*   edge = (const int*)d_in[6];
    const int*   perm = (const int*)d_in[7];

    const int N = in_sizes[7];
    const int E = in_sizes[6] / 2;
    const int* row = edge;
    const int* col = edge + E;

    char* wsb = (char*)d_ws;
    size_t off = 0;
    auto alloc = [&](size_t bytes) -> void* {
        void* p = wsb + off;
        off = (off + bytes + 255) & ~(size_t)255;
        return p;
    };
    int*   bucket   = (int*)  alloc((size_t)N * CAP * 4);    // 25.6 MB
    int*   cnt      = (int*)  alloc((size_t)N * 4);
    int2*  bins     = (int2*) alloc((size_t)8 * BINCAP * 8); // 14.4 MB
    int*   bincur   = (int*)  alloc(8 * 4);
    uint*  G        = (uint*) alloc((size_t)N * 64 * 4);     // packed, 25.6 MB
    uint*  H        = (uint*) alloc((size_t)N * 64 * 4);
    float* colpart  = (float*)alloc((size_t)GG * 64 * 4);
    float* colpart2 = (float*)alloc((size_t)(GG / RB) * 64 * 4);
    float* wsv      = (float*)alloc(64 * 4);
    float* lossacc  = (float*)alloc(2 * 4);

    hipMemsetAsync(cnt, 0, (size_t)N * 4, stream);
    hipMemsetAsync(bincur, 0, 8 * 4, stream);
    hipMemsetAsync(lossacc, 0, 8, stream);

    const int bound = (N + 7) / 8;   // col-range per XCD group
    partition_edges<<<400, 256, 0, stream>>>(row, col, bins, bincur, E, bound);
    place_binned<<<1024, 256, 0, stream>>>(bins, bincur, bucket, cnt);

    // layer 1: G = (X @ W1) * dis (both branches packed), aggregate+relu -> H
    gemm1_both<<<1024, 256, 0, stream>>>(x, W1, perm, cnt, G, N);
    conv_packed<0><<<GG, 256, 0, stream>>>(G, bucket, cnt, b1, H, nullptr, N);
    // layer 2: G = (H @ W2) * dis, aggregate -> z (in H) + colpart
    gemm2_both<<<1024, 256, 0, stream>>>(H, W2, cnt, G, N);
    conv_packed<1><<<GG, 256, 0, stream>>>(G, bucket, cnt, b2, H, colpart, N);

    colreduce_kernel<<<GG / RB, 256, 0, stream>>>(colpart, colpart2);
    summary_kernel<<<1, 256, 0, stream>>>(colpart2, Wdgi, wsv, GG / RB, 1.0f / N);
    loss_kernel<<<1024, 256, 0, stream>>>(H, wsv, lossacc, N);
    finalize_kernel<<<1, 1, 0, stream>>>(lossacc, (float*)d_out, 1.0f / N);
}

// Round 9
// 291.369 us; speedup vs baseline: 1.2838x; 1.2838x over previous
//
#include <hip/hip_runtime.h>
#include <hip/hip_bf16.h>
#include <math.h>

#define CAP 64
#define GG 2048     // conv grid (colpart rows)
#define RB 32       // colpart rows per stage-A block

typedef __hip_bfloat16 bf16;
typedef unsigned int uint;
typedef unsigned short ushort;
typedef short bf16x8 __attribute__((ext_vector_type(8)));   // 8 bf16 (4 VGPRs)
typedef float f32x4 __attribute__((ext_vector_type(4)));

__device__ __forceinline__ bf16  f2b(float x) { return __float2bfloat16(x); }
__device__ __forceinline__ short f2bs(float x) {
    bf16 b = __float2bfloat16(x);
    return *reinterpret_cast<short*>(&b);
}
// packed pos/neg: low 16 bits = bf16(pos), high 16 bits = bf16(neg)
__device__ __forceinline__ float posf(uint u) { return __uint_as_float(u << 16); }
__device__ __forceinline__ float negf(uint u) { return __uint_as_float(u & 0xFFFF0000u); }
__device__ __forceinline__ uint  packbf(float p, float n) {
    bf16 bp = f2b(p), bn = f2b(n);
    ushort up = *reinterpret_cast<ushort*>(&bp);
    ushort un = *reinterpret_cast<ushort*>(&bn);
    return (uint)up | ((uint)un << 16);
}

// ---- bucket build, XCD-affinity grouped (R7 version) ----------------------
__global__ __launch_bounds__(256) void place_grouped(
        const int* __restrict__ row, const int* __restrict__ col,
        int* __restrict__ bucket, int* __restrict__ cnt, int E, int bound) {
    int g    = blockIdx.x & 7;
    int kb   = blockIdx.x >> 3;
    int K    = gridDim.x >> 3;
    int lo   = g * bound, hi = lo + bound;
    int tid  = kb * blockDim.x + threadIdx.x;
    int nthr = K * blockDim.x;
    int E4   = E >> 2;
    const int4* col4 = (const int4*)col;
    for (int i = tid; i < E4; i += nthr) {
        int4 c4 = col4[i];
        int e0 = i << 2;
        if (c4.x >= lo && c4.x < hi) {
            int pos = atomicAdd(&cnt[c4.x], 1);
            if (pos < CAP) bucket[(size_t)c4.x * CAP + pos] = row[e0];
        }
        if (c4.y >= lo && c4.y < hi) {
            int pos = atomicAdd(&cnt[c4.y], 1);
            if (pos < CAP) bucket[(size_t)c4.y * CAP + pos] = row[e0 + 1];
        }
        if (c4.z >= lo && c4.z < hi) {
            int pos = atomicAdd(&cnt[c4.z], 1);
            if (pos < CAP) bucket[(size_t)c4.z * CAP + pos] = row[e0 + 2];
        }
        if (c4.w >= lo && c4.w < hi) {
            int pos = atomicAdd(&cnt[c4.w], 1);
            if (pos < CAP) bucket[(size_t)c4.w * CAP + pos] = row[e0 + 3];
        }
    }
    for (int e = (E4 << 2) + tid; e < E; e += nthr) {
        int c = col[e];
        if (c >= lo && c < hi) {
            int pos = atomicAdd(&cnt[c], 1);
            if (pos < CAP) bucket[(size_t)c * CAP + pos] = row[e];
        }
    }
}

// ---- layer-1 GEMM via MFMA: out = pack((X@W1)*dv, (X[perm]@W1)*dv) --------
// wave per 16-node tile. A: row=lane&15, k=(lane>>4)*8+i. B: col=lane&15,
// k=(lane>>4)*8+i. D: col=lane&15 (outdim), row=(lane>>4)*4+reg (node).
__global__ __launch_bounds__(256) void gemm1_mfma(
        const float* __restrict__ X, const float* __restrict__ W,
        const int* __restrict__ perm, const int* __restrict__ cnt,
        uint* __restrict__ out, int n) {
    int lane = threadIdx.x & 63, wid = threadIdx.x >> 6;
    int l15 = lane & 15, lg = lane >> 4;
    // B fragments of W: bfr[kt][nt], loaded once per wave (L1-resident)
    bf16x8 bfr[2][4];
#pragma unroll
    for (int kt = 0; kt < 2; kt++)
#pragma unroll
        for (int nt = 0; nt < 4; nt++)
#pragma unroll
            for (int i = 0; i < 8; i++)
                bfr[kt][nt][i] = f2bs(W[(kt * 32 + lg * 8 + i) * 64 + nt * 16 + l15]);
    int ntiles = (n + 15) >> 4;
    for (int t = blockIdx.x * 4 + wid; t < ntiles; t += gridDim.x * 4) {
        int rowA = t * 16 + l15;
        if (rowA >= n) rowA = n - 1;
        int prow = perm[rowA];
        const float4* xp = (const float4*)(X + (size_t)rowA * 64);
        const float4* xn = (const float4*)(X + (size_t)prow * 64);
        bf16x8 ap[2], an[2];
#pragma unroll
        for (int kt = 0; kt < 2; kt++) {
            float4 p0 = xp[kt * 8 + lg * 2], p1 = xp[kt * 8 + lg * 2 + 1];
            float4 n0 = xn[kt * 8 + lg * 2], n1 = xn[kt * 8 + lg * 2 + 1];
            ap[kt][0] = f2bs(p0.x); ap[kt][1] = f2bs(p0.y);
            ap[kt][2] = f2bs(p0.z); ap[kt][3] = f2bs(p0.w);
            ap[kt][4] = f2bs(p1.x); ap[kt][5] = f2bs(p1.y);
            ap[kt][6] = f2bs(p1.z); ap[kt][7] = f2bs(p1.w);
            an[kt][0] = f2bs(n0.x); an[kt][1] = f2bs(n0.y);
            an[kt][2] = f2bs(n0.z); an[kt][3] = f2bs(n0.w);
            an[kt][4] = f2bs(n1.x); an[kt][5] = f2bs(n1.y);
            an[kt][6] = f2bs(n1.z); an[kt][7] = f2bs(n1.w);
        }
        f32x4 accp[4], accn[4];
#pragma unroll
        for (int nt = 0; nt < 4; nt++) { accp[nt] = (f32x4)0.f; accn[nt] = (f32x4)0.f; }
#pragma unroll
        for (int nt = 0; nt < 4; nt++) {
            accp[nt] = __builtin_amdgcn_mfma_f32_16x16x32_bf16(ap[0], bfr[0][nt], accp[nt], 0, 0, 0);
            accp[nt] = __builtin_amdgcn_mfma_f32_16x16x32_bf16(ap[1], bfr[1][nt], accp[nt], 0, 0, 0);
            accn[nt] = __builtin_amdgcn_mfma_f32_16x16x32_bf16(an[0], bfr[0][nt], accn[nt], 0, 0, 0);
            accn[nt] = __builtin_amdgcn_mfma_f32_16x16x32_bf16(an[1], bfr[1][nt], accn[nt], 0, 0, 0);
        }
        float dvr[4];
#pragma unroll
        for (int reg = 0; reg < 4; reg++) {
            int node = t * 16 + lg * 4 + reg;
            dvr[reg] = node < n ? rsqrtf((float)cnt[node] + 1.0f) : 0.f;
        }
#pragma unroll
        for (int nt = 0; nt < 4; nt++)
#pragma unroll
            for (int reg = 0; reg < 4; reg++) {
                int node = t * 16 + lg * 4 + reg;
                if (node < n)
                    out[(size_t)node * 64 + nt * 16 + l15] =
                        packbf(accp[nt][reg] * dvr[reg], accn[nt][reg] * dvr[reg]);
            }
    }
}

// ---- layer-2 GEMM via MFMA, packed bf16 input ------------------------------
__global__ __launch_bounds__(256) void gemm2_mfma(
        const uint* __restrict__ H, const float* __restrict__ W,
        const int* __restrict__ cnt, uint* __restrict__ out, int n) {
    int lane = threadIdx.x & 63, wid = threadIdx.x >> 6;
    int l15 = lane & 15, lg = lane >> 4;
    bf16x8 bfr[2][4];
#pragma unroll
    for (int kt = 0; kt < 2; kt++)
#pragma unroll
        for (int nt = 0; nt < 4; nt++)
#pragma unroll
            for (int i = 0; i < 8; i++)
                bfr[kt][nt][i] = f2bs(W[(kt * 32 + lg * 8 + i) * 64 + nt * 16 + l15]);
    int ntiles = (n + 15) >> 4;
    for (int t = blockIdx.x * 4 + wid; t < ntiles; t += gridDim.x * 4) {
        int rowA = t * 16 + l15;
        if (rowA >= n) rowA = n - 1;
        const uint4* h = (const uint4*)(H + (size_t)rowA * 64);
        bf16x8 ap[2], an[2];
#pragma unroll
        for (int kt = 0; kt < 2; kt++) {
            uint4 u0 = h[kt * 8 + lg * 2], u1 = h[kt * 8 + lg * 2 + 1];
            uint uu[8] = {u0.x, u0.y, u0.z, u0.w, u1.x, u1.y, u1.z, u1.w};
#pragma unroll
            for (int i = 0; i < 8; i++) {
                ap[kt][i] = (short)(uu[i] & 0xFFFFu);
                an[kt][i] = (short)(uu[i] >> 16);
            }
        }
        f32x4 accp[4], accn[4];
#pragma unroll
        for (int nt = 0; nt < 4; nt++) { accp[nt] = (f32x4)0.f; accn[nt] = (f32x4)0.f; }
#pragma unroll
        for (int nt = 0; nt < 4; nt++) {
            accp[nt] = __builtin_amdgcn_mfma_f32_16x16x32_bf16(ap[0], bfr[0][nt], accp[nt], 0, 0, 0);
            accp[nt] = __builtin_amdgcn_mfma_f32_16x16x32_bf16(ap[1], bfr[1][nt], accp[nt], 0, 0, 0);
            accn[nt] = __builtin_amdgcn_mfma_f32_16x16x32_bf16(an[0], bfr[0][nt], accn[nt], 0, 0, 0);
            accn[nt] = __builtin_amdgcn_mfma_f32_16x16x32_bf16(an[1], bfr[1][nt], accn[nt], 0, 0, 0);
        }
        float dvr[4];
#pragma unroll
        for (int reg = 0; reg < 4; reg++) {
            int node = t * 16 + lg * 4 + reg;
            dvr[reg] = node < n ? rsqrtf((float)cnt[node] + 1.0f) : 0.f;
        }
#pragma unroll
        for (int nt = 0; nt < 4; nt++)
#pragma unroll
            for (int reg = 0; reg < 4; reg++) {
                int node = t * 16 + lg * 4 + reg;
                if (node < n)
                    out[(size_t)node * 64 + nt * 16 + l15] =
                        packbf(accp[nt][reg] * dvr[reg], accn[nt][reg] * dvr[reg]);
            }
    }
}

// ---- fused GCN aggregation, packed pos/neg (wave/node, lane=dim) ----------
template <int MODE>
__global__ __launch_bounds__(256) void conv_packed(
        const uint* __restrict__ g, const int* __restrict__ bucket,
        const int* __restrict__ cnt, const float* __restrict__ bias,
        uint* __restrict__ out, float* __restrict__ colpart, int n) {
    int lane = threadIdx.x & 63, wid = threadIdx.x >> 6;
    __shared__ float s[256];
    float colp  = 0.f;
    float blane = bias[lane];
    int wstart = blockIdx.x * 4 + wid, wstride = gridDim.x * 4;
    for (int v = wstart; v < n; v += wstride) {
        int cf = cnt[v];
        int c  = cf > CAP ? CAP : cf;
        float dv = rsqrtf((float)cf + 1.0f);
        size_t vo = (size_t)v * 64 + lane;
        uint su = g[vo];
        float a0p = posf(su), a1p = 0.f, a2p = 0.f, a3p = 0.f;   // self in a0
        float a0n = negf(su), a1n = 0.f, a2n = 0.f, a3n = 0.f;
        const int*  bk  = bucket + (size_t)v * CAP;
        const int4* bk4 = (const int4*)bk;
        int nq8 = c >> 3;
        for (int q = 0; q < nq8; q++) {
            int4 ra = bk4[2 * q], rb = bk4[2 * q + 1];
            uint u0 = g[(size_t)ra.x * 64 + lane];
            uint u1 = g[(size_t)ra.y * 64 + lane];
            uint u2 = g[(size_t)ra.z * 64 + lane];
            uint u3 = g[(size_t)ra.w * 64 + lane];
            uint u4 = g[(size_t)rb.x * 64 + lane];
            uint u5 = g[(size_t)rb.y * 64 + lane];
            uint u6 = g[(size_t)rb.z * 64 + lane];
            uint u7 = g[(size_t)rb.w * 64 + lane];
            a0p += posf(u0) + posf(u4); a0n += negf(u0) + negf(u4);
            a1p += posf(u1) + posf(u5); a1n += negf(u1) + negf(u5);
            a2p += posf(u2) + posf(u6); a2n += negf(u2) + negf(u6);
            a3p += posf(u3) + posf(u7); a3n += negf(u3) + negf(u7);
        }
        int i = nq8 << 3;
        if (c - i >= 4) {
            int4 r = bk4[i >> 2];
            uint u0 = g[(size_t)r.x * 64 + lane];
            uint u1 = g[(size_t)r.y * 64 + lane];
            uint u2 = g[(size_t)r.z * 64 + lane];
            uint u3 = g[(size_t)r.w * 64 + lane];
            a0p += posf(u0); a0n += negf(u0);
            a1p += posf(u1); a1n += negf(u1);
            a2p += posf(u2); a2n += negf(u2);
            a3p += posf(u3); a3n += negf(u3);
            i += 4;
        }
        for (; i < c; i++) {
            uint u = g[(size_t)bk[i] * 64 + lane];
            a0p += posf(u);
            a0n += negf(u);
        }
        float sp = (a0p + a1p) + (a2p + a3p);
        float sn = (a0n + a1n) + (a2n + a3n);
        float rp = fmaf(dv, sp, blane);
        float rn = fmaf(dv, sn, blane);
        if (MODE == 0) {
            out[vo] = packbf(fmaxf(rp, 0.f), fmaxf(rn, 0.f));
        } else {
            out[vo] = packbf(rp, rn);
            colp += rp;
        }
    }
    if (MODE == 1) {
        s[wid * 64 + lane] = colp;
        __syncthreads();
        if (wid == 0) {
            float t = s[lane] + s[64 + lane] + s[128 + lane] + s[192 + lane];
            colpart[(size_t)blockIdx.x * 64 + lane] = t;
        }
    }
}

// ---- stage A: sum RB colpart rows per block -> colpart2 --------------------
__global__ __launch_bounds__(256) void colreduce_kernel(
        const float* __restrict__ colpart, float* __restrict__ colpart2) {
    int lane = threadIdx.x & 63, w = threadIdx.x >> 6;
    __shared__ float s4[4][64];
    float t = 0.f;
    int base = blockIdx.x * RB;
    for (int g = w; g < RB; g += 4) t += colpart[(size_t)(base + g) * 64 + lane];
    s4[w][lane] = t;
    __syncthreads();
    if (w == 0)
        colpart2[(size_t)blockIdx.x * 64 + lane] =
            s4[0][lane] + s4[1][lane] + s4[2][lane] + s4[3][lane];
}

// ---- summary + ws = W_dgi @ sigmoid(mean(pos_z)) ---------------------------
__global__ void summary_kernel(const float* __restrict__ colpart,
                               const float* __restrict__ Wdgi,
                               float* __restrict__ wsv, int G, float invN) {
    __shared__ float sm[64];
    __shared__ float s4[4][64];
    int lane = threadIdx.x & 63, w = threadIdx.x >> 6;
    float t = 0.f;
    for (int g = w; g < G; g += 4) t += colpart[(size_t)g * 64 + lane];
    s4[w][lane] = t;
    __syncthreads();
    if (w == 0) {
        t = s4[0][lane] + s4[1][lane] + s4[2][lane] + s4[3][lane];
        sm[lane] = 1.f / (1.f + expf(-t * invN));
    }
    __syncthreads();
    if (threadIdx.x < 64) {
        float a = 0.f;
        for (int j = 0; j < 64; j++) a += Wdgi[threadIdx.x * 64 + j] * sm[j];
        wsv[threadIdx.x] = a;
    }
}

// ---- both losses in one pass (packed z) ------------------------------------
__global__ __launch_bounds__(256) void loss_kernel(
        const uint* __restrict__ z, const float* __restrict__ wsv,
        float* __restrict__ lossacc, int n) {
    int lane = threadIdx.x & 63, wid = threadIdx.x >> 6;
    __shared__ float s[16];
    float wlane = wsv[lane];
    float lp = 0.f, ln = 0.f;
    int wstart = blockIdx.x * 4 + wid, wstride = gridDim.x * 4;
    for (int v = wstart; v < n; v += wstride) {
        uint u = z[(size_t)v * 64 + lane];
        float p = posf(u) * wlane;
        float q = negf(u) * wlane;
        for (int off = 32; off; off >>= 1) {
            p += __shfl_xor(p, off, 64);
            q += __shfl_xor(q, off, 64);
        }
        if (lane == 0) {
            lp += -logf(1.f / (1.f + expf(-p)) + 1e-15f);
            ln += -logf(1.f / (1.f + expf( q)) + 1e-15f);
        }
    }
    if (lane == 0) { s[wid] = lp; s[8 + wid] = ln; }
    __syncthreads();
    if (threadIdx.x == 0) atomicAdd(&lossacc[0], s[0] + s[1] + s[2] + s[3]);
    if (threadIdx.x == 1) atomicAdd(&lossacc[1], s[8] + s[9] + s[10] + s[11]);
}

__global__ void finalize_kernel(const float* __restrict__ lossacc,
                                float* __restrict__ out, float invN) {
    out[0] = (lossacc[0] + lossacc[1]) * invN;
}

// ---------------------------------------------------------------------------
extern "C" void kernel_launch(void* const* d_in, const int* in_sizes, int n_in,
                              void* d_out, int out_size, void* d_ws, size_t ws_size,
                              hipStream_t stream) {
    const float* x    = (const float*)d_in[0];
    const float* W1   = (const float*)d_in[1];
    const float* b1   = (const float*)d_in[2];
    const float* W2   = (const float*)d_in[3];
    const float* b2   = (const float*)d_in[4];
    const float* Wdgi = (const float*)d_in[5];
    const int*   edge = (const int*)d_in[6];
    const int*   perm = (const int*)d_in[7];

    const int N = in_sizes[7];
    const int E = in_sizes[6] / 2;
    const int* row = edge;
    const int* col = edge + E;

    char* wsb = (char*)d_ws;
    size_t off = 0;
    auto alloc = [&](size_t bytes) -> void* {
        void* p = wsb + off;
        off = (off + bytes + 255) & ~(size_t)255;
        return p;
    };
    int*   bucket   = (int*)  alloc((size_t)N * CAP * 4);   // 25.6 MB
    int*   cnt      = (int*)  alloc((size_t)N * 4);
    uint*  G        = (uint*) alloc((size_t)N * 64 * 4);    // packed, 25.6 MB
    uint*  H        = (uint*) alloc((size_t)N * 64 * 4);
    float* colpart  = (float*)alloc((size_t)GG * 64 * 4);
    float* colpart2 = (float*)alloc((size_t)(GG / RB) * 64 * 4);
    float* wsv      = (float*)alloc(64 * 4);
    float* lossacc  = (float*)alloc(2 * 4);

    hipMemsetAsync(cnt, 0, (size_t)N * 4, stream);
    hipMemsetAsync(lossacc, 0, 8, stream);

    const int bound = (N + 7) / 8;   // col-range per XCD group
    place_grouped<<<1024, 256, 0, stream>>>(row, col, bucket, cnt, E, bound);

    // layer 1: G = (X @ W1) * dis (both branches packed), aggregate+relu -> H
    gemm1_mfma<<<1024, 256, 0, stream>>>(x, W1, perm, cnt, G, N);
    conv_packed<0><<<GG, 256, 0, stream>>>(G, bucket, cnt, b1, H, nullptr, N);
    // layer 2: G = (H @ W2) * dis, aggregate -> z (in H) + colpart
    gemm2_mfma<<<1024, 256, 0, stream>>>(H, W2, cnt, G, N);
    conv_packed<1><<<GG, 256, 0, stream>>>(G, bucket, cnt, b2, H, colpart, N);

    colreduce_kernel<<<GG / RB, 256, 0, stream>>>(colpart, colpart2);
    summary_kernel<<<1, 256, 0, stream>>>(colpart2, Wdgi, wsv, GG / RB, 1.0f / N);
    loss_kernel<<<1024, 256, 0, stream>>>(H, wsv, lossacc, N);
    finalize_kernel<<<1, 1, 0, stream>>>(lossacc, (float*)d_out, 1.0f / N);
}